// Round 9
// baseline (55.108 us; speedup 1.0000x reference)
//
#include <hip/hip_runtime.h>
#include <hip/hip_bf16.h>

#define NNODE 25
#define HID   128
#define GB    16
#define BLOCK 256
#define KTOT  256
#define SPAD  264
#define XTW   40     // Xtb row stride (u16): 80B -> 16B-aligned rows, 2-way banks

// ws layout (bytes)
#define WS_WT   0        // u16 [128][256]  W2cat^T bf16 (W2r part pre-scaled by 1/25)
#define WS_FLAG 65536    // u32 producer-done counter (memset to 0 each call)

typedef __attribute__((ext_vector_type(8))) short short8;
typedef __attribute__((ext_vector_type(4))) float f32x4;
typedef __attribute__((ext_vector_type(2))) float f32x2;

__device__ inline unsigned short f2bf(float f) {
  __hip_bfloat16 h = __float2bfloat16(f);
  unsigned short u; __builtin_memcpy(&u, &h, 2); return u;
}

// Xbf cell: node n (0..24), batch g (0..15); 8 bf16/cell; g XOR-swizzled
#define XB(n, g) (((n)*GB + ((g) ^ ((n) & 15))) * 8)

__global__ __launch_bounds__(BLOCK, 5) void gnn_all(
    const float* __restrict__ x,        // [B][25][3]
    const int*   __restrict__ ei,       // [2][64]
    const float* __restrict__ W1l,      // [3][128]
    const float* __restrict__ W1r,      // [3][128]
    const float* __restrict__ b1,       // [128]
    const float* __restrict__ W2l,      // [128][128]
    const float* __restrict__ W2r,      // [128][128]
    const float* __restrict__ b2,       // [128]
    unsigned char* ws,
    float* __restrict__ out)            // [B][128]
{
  __shared__ float Mm[NNODE*NNODE];
  __shared__ float cnt[NNODE];
  __shared__ float cvecs[NNODE];
  __shared__ __align__(16) unsigned short Mtb[32][32];
  __shared__ __align__(16) unsigned short W1bs[HID*8];
  __shared__ __align__(16) unsigned short Xtb[3][GB][XTW];  // bf16 x[d][g][m]
  __shared__ __align__(16) unsigned short Xbf[NNODE*GB*8];  // {agg0..2, x0..2, 0, 0}
  __shared__ __align__(16) unsigned short Sbf[GB][SPAD];    // [s1(128) | s2*25(128)]

  const int tid  = threadIdx.x;
  const int b0   = blockIdx.x * GB;
  const int wave = tid >> 6;
  const int lane = tid & 63;
  const int r    = lane & 15;
  const int kg   = lane >> 4;
  const f32x4 zz = {0.f, 0.f, 0.f, 0.f};

  // ---- producers: blocks 0..127 convert one 256-elem slice of Wt ----
  if (blockIdx.x < 128) {
    int i = blockIdx.x*256 + tid;
    int o = i >> 8, k = i & 255;
    float v = (k < HID) ? W2l[k*HID + o] : W2r[(k-HID)*HID + o] * (1.f/NNODE);
    ((unsigned short*)(ws + WS_WT))[o*KTOT + k] = f2bf(v);
    __threadfence();
    __syncthreads();
    if (tid == 0) atomicAdd((unsigned int*)(ws + WS_FLAG), 1u);
  }

  // ---- phase A0: issue x loads (float4) first to hide HBM latency ----
  f32x4 xv[2];
  int   i4v[2];
  #pragma unroll
  for (int t = 0; t < 2; ++t) {
    int i4 = tid + t*BLOCK;
    i4v[t] = i4;
    if (i4 < GB*75/4) xv[t] = ((const f32x4*)(x + (size_t)b0*75))[i4];
  }
  // zero M counts; zero Xtb pad tail m in [25,32) (disjoint from scatter m<25)
  for (int i = tid; i < NNODE*NNODE; i += BLOCK) Mm[i] = 0.f;
  if (tid < NNODE) cnt[tid] = 0.f;
  for (int i = tid; i < 3*GB*7; i += BLOCK) {
    int d = i / (GB*7), rm = i % (GB*7);
    Xtb[d][rm/7][25 + rm%7] = 0;
  }
  for (int p = tid; p < NNODE*GB; p += BLOCK)              // Xbf slots 6,7 = 0
    *(unsigned int*)&Xbf[XB(p >> 4, p & 15) + 6] = 0u;
  __syncthreads();   // B1: Mm/cnt zeroed

  // ---- phase A1: edge atomics || W1b build || x scatter ----
  if (tid < 64) {
    int s = ei[tid], d = ei[64 + tid];
    atomicAdd(&Mm[d*NNODE + s], 1.f);
    atomicAdd(&cnt[d], 1.f);
  }
  if (tid >= 64 && tid < 192) {
    int c = tid - 64;
    unsigned short* p = &W1bs[c*8];
    p[0] = f2bf(W1l[c]);       p[1] = f2bf(W1l[HID+c]);  p[2] = f2bf(W1l[2*HID+c]);
    p[3] = f2bf(W1r[c]);       p[4] = f2bf(W1r[HID+c]);  p[5] = f2bf(W1r[2*HID+c]);
    p[6] = 0;                  p[7] = 0;
  }
  #pragma unroll
  for (int t = 0; t < 2; ++t) {
    if (i4v[t] < GB*75/4) {
      #pragma unroll
      for (int j = 0; j < 4; ++j) {
        int e = i4v[t]*4 + j;
        int g = e / 75, rm = e - g*75;
        int n = rm / 3, d = rm - n*3;
        unsigned short bv = f2bf(xv[t][j]);
        Xtb[d][g][n] = bv;
        Xbf[XB(n, g) + 3 + d] = bv;
      }
    }
  }
  __syncthreads();   // B2: counts + W1bs + x in LDS

  // ---- phase A2: normalize M -> Mtb bf16 (write normalized back for cvec) ----
  for (int i = tid; i < 1024; i += BLOCK) {
    int n = i >> 5, m = i & 31;
    float v = 0.f;
    if (n < NNODE && m < NNODE) {
      v = Mm[n*NNODE + m] / fmaxf(cnt[n], 1.f);
      Mm[n*NNODE + m] = v;
    }
    ((unsigned short*)Mtb)[i] = f2bf(v);
  }
  __syncthreads();   // B3: Mtb + normalized Mm ready

  // ---- phase B: agg via MFMA (waves 0..2, one d each) || cvec (wave 3) ----
  if (wave < 3) {
    const int d = wave;
    short8 mb0 = *(const short8*)&Mtb[r][kg*8];        // B[k=m][col=n], n=r
    short8 mb1 = *(const short8*)&Mtb[16 + r][kg*8];   // n=16+r (rows >=25 zero)
    short8 af  = *(const short8*)&Xtb[d][r][kg*8];     // A[row=g][k=m]
    f32x4 g0 = __builtin_amdgcn_mfma_f32_16x16x32_bf16(af, mb0, zz, 0, 0, 0);
    f32x4 g1 = __builtin_amdgcn_mfma_f32_16x16x32_bf16(af, mb1, zz, 0, 0, 0);
    #pragma unroll
    for (int q = 0; q < 4; ++q) {
      int g = kg*4 + q;                  // C row = batch (within block)
      Xbf[XB(r, g) + d] = f2bf(g0[q]);   // C col = node n = r
      if (r < 9) Xbf[XB(16 + r, g) + d] = f2bf(g1[q]);
    }
  } else if (wave == 3 && lane < NNODE) {
    float a = 0.f;
    #pragma unroll 5
    for (int n = 0; n < NNODE; ++n) a += Mm[n*NNODE + lane];
    cvecs[lane] = a * (1.f/NNODE);
  }
  __syncthreads();   // B4

  // ---- phase C: stage 1 via MFMA, 2 nodes per iteration (K slots 0,1) ----
  {
    const int c0 = wave * 32;
    const int cA = c0 + r, cB = c0 + 16 + r;
    const short8 w1A = *(const short8*)&W1bs[cA * 8];
    const short8 w1B = *(const short8*)&W1bs[cB * 8];
    const short8 z8  = {0,0,0,0,0,0,0,0};
    // slot-masked B fragments: slot0 -> B rows 0..7, slot1 -> B rows 8..15
    const short8 bA0 = (kg == 0) ? w1A : z8;
    const short8 bA1 = (kg == 1) ? w1A : z8;
    const short8 bB0 = (kg == 0) ? w1B : z8;
    const short8 bB1 = (kg == 1) ? w1B : z8;
    const float biasA = b1[cA], biasB = b1[cB];
    const f32x4 cbA = {biasA, biasA, biasA, biasA};
    const f32x4 cbB = {biasB, biasB, biasB, biasB};
    f32x2 s1[4] = {}, s2[4] = {};
    for (int ng = 0; ng < 12; ++ng) {    // nodes 2ng (slot0), 2ng+1 (slot1)
      short8 a = *(const short8*)&Xbf[XB(2*ng + (kg & 1), r)];
      f32x4 h0e = __builtin_amdgcn_mfma_f32_16x16x32_bf16(a, bA0, cbA, 0, 0, 0);
      f32x4 h1e = __builtin_amdgcn_mfma_f32_16x16x32_bf16(a, bB0, cbB, 0, 0, 0);
      f32x4 h0o = __builtin_amdgcn_mfma_f32_16x16x32_bf16(a, bA1, cbA, 0, 0, 0);
      f32x4 h1o = __builtin_amdgcn_mfma_f32_16x16x32_bf16(a, bB1, cbB, 0, 0, 0);
      const float cv0 = cvecs[2*ng], cv1 = cvecs[2*ng + 1];
      const f32x2 cvv0 = {cv0, cv0}, cvv1 = {cv1, cv1};
      #pragma unroll
      for (int q = 0; q < 4; ++q) {
        f32x2 ve; ve.x = fmaxf(h0e[q], 0.f); ve.y = fmaxf(h1e[q], 0.f);
        f32x2 vo; vo.x = fmaxf(h0o[q], 0.f); vo.y = fmaxf(h1o[q], 0.f);
        s1[q] += cvv0 * ve; s2[q] += ve;
        s1[q] += cvv1 * vo; s2[q] += vo;
      }
    }
    {  // epilogue: node 24 via slot 0 only
      short8 a = *(const short8*)&Xbf[XB(24, r)];
      f32x4 h0 = __builtin_amdgcn_mfma_f32_16x16x32_bf16(a, bA0, cbA, 0, 0, 0);
      f32x4 h1 = __builtin_amdgcn_mfma_f32_16x16x32_bf16(a, bB0, cbB, 0, 0, 0);
      const float cv = cvecs[24];
      const f32x2 cvv = {cv, cv};
      #pragma unroll
      for (int q = 0; q < 4; ++q) {
        f32x2 v; v.x = fmaxf(h0[q], 0.f); v.y = fmaxf(h1[q], 0.f);
        s1[q] += cvv * v;
        s2[q] += v;
      }
    }
    #pragma unroll
    for (int q = 0; q < 4; ++q) {
      int g = kg*4 + q;
      Sbf[g][cA]       = f2bf(s1[q].x);
      Sbf[g][cB]       = f2bf(s1[q].y);
      Sbf[g][HID + cA] = f2bf(s2[q].x);   // 1/25 folded into Wt's W2r half
      Sbf[g][HID + cB] = f2bf(s2[q].y);
    }
  }

  // ---- gate: Wt must be complete (producers are blocks 0..127, dispatched first) ----
  if (tid == 0) {
    const unsigned int* flag = (const unsigned int*)(ws + WS_FLAG);
    while (__hip_atomic_load(flag, __ATOMIC_ACQUIRE, __HIP_MEMORY_SCOPE_AGENT) < 128u)
      __builtin_amdgcn_s_sleep(2);
  }
  __syncthreads();   // B5: Sbf visible + gate broadcast

  // ---- phase D: out[16x128] = S[16x256] @ W2cat via MFMA ----
  {
    const int n0 = wave * 32;
    const unsigned short* Wt = (const unsigned short*)(ws + WS_WT);
    const unsigned short* WtA = Wt + (size_t)(n0 + r)      * KTOT;
    const unsigned short* WtB = Wt + (size_t)(n0 + 16 + r) * KTOT;
    f32x4 acc0 = zz, acc1 = zz;
    #pragma unroll 4
    for (int kt = 0; kt < 8; ++kt) {
      const int kb = kt*32 + kg*8;
      short8 a  = *(const short8*)&Sbf[r][kb];
      short8 bA = *(const short8*)&WtA[kb];
      short8 bB = *(const short8*)&WtB[kb];
      acc0 = __builtin_amdgcn_mfma_f32_16x16x32_bf16(a, bA, acc0, 0, 0, 0);
      acc1 = __builtin_amdgcn_mfma_f32_16x16x32_bf16(a, bB, acc1, 0, 0, 0);
    }
    const int colA = n0 + r, colB = n0 + 16 + r;
    const float bA2 = b2[colA], bB2 = b2[colB];
    #pragma unroll
    for (int q = 0; q < 4; ++q) {
      const int row = kg*4 + q;
      out[(size_t)(b0+row)*HID + colA] = acc0[q] + bA2;
      out[(size_t)(b0+row)*HID + colB] = acc1[q] + bB2;
    }
  }
}

extern "C" void kernel_launch(void* const* d_in, const int* in_sizes, int n_in,
                              void* d_out, int out_size, void* d_ws, size_t ws_size,
                              hipStream_t stream) {
  (void)n_in; (void)out_size; (void)ws_size;
  const float* x   = (const float*)d_in[0];
  const int*   ei  = (const int*)  d_in[1];
  const float* W1l = (const float*)d_in[2];
  const float* W1r = (const float*)d_in[3];
  const float* b1  = (const float*)d_in[4];
  const float* W2l = (const float*)d_in[5];
  const float* W2r = (const float*)d_in[6];
  const float* b2  = (const float*)d_in[7];
  float* out = (float*)d_out;
  unsigned char* ws = (unsigned char*)d_ws;

  const int B = in_sizes[0] / (NNODE*3);   // 16384
  hipMemsetAsync(ws + WS_FLAG, 0, 4, stream);
  gnn_all<<<dim3(B / GB), dim3(BLOCK), 0, stream>>>(
      x, ei, W1l, W1r, b1, W2l, W2r, b2, ws, out);
}

// Round 10
// 29.854 us; speedup vs baseline: 1.8459x; 1.8459x over previous
//
#include <hip/hip_runtime.h>
#include <hip/hip_bf16.h>

#define NNODE 25
#define HID   128
#define GBW   16     // batches per wave (= per 64-thread block)
#define KTOT  256
#define SPAD  264
#define XTW   40     // Xtb row stride (u16): 80B rows, 16B-aligned

// ws layout (bytes)
#define WS_WT   0        // u16 [128][256]  W2cat^T bf16 (W2r half pre-scaled by 1/25)
#define WS_MTB  65536    // u16 [32][32]    M bf16, zero-padded
#define WS_CVEC 67584    // f32 [32]        (1/25) * colsum(M)
#define WS_W1B  67712    // u16 [128][8]    0.25*{W1l[0..2][c], W1r[0..2][c], 0, 0}

typedef __attribute__((ext_vector_type(8))) short short8;
typedef __attribute__((ext_vector_type(4))) float f32x4;
typedef __attribute__((ext_vector_type(2))) float f32x2;

__device__ inline unsigned short f2bf(float f) {
  __hip_bfloat16 h = __float2bfloat16(f);
  unsigned short u; __builtin_memcpy(&u, &h, 2); return u;
}

// Xbf cell: node n (0..24), batch g (0..15); 8 bf16/cell; g XOR-swizzled
#define XB(n, g) (((n)*GBW + ((g) ^ ((n) & 15))) * 8)

__global__ __launch_bounds__(256) void prep(
    const float* __restrict__ W2l, const float* __restrict__ W2r,
    const float* __restrict__ W1l, const float* __restrict__ W1r,
    const int*   __restrict__ ei,  unsigned char* __restrict__ ws)
{
  const int blk = blockIdx.x, tid = threadIdx.x;
  if (blk < 128) {
    // Wt[o][k] = bf16(W2cat[k][o]); coalesced reads (o along tid), scattered writes
    unsigned short* Wt = (unsigned short*)(ws + WS_WT);
    int o = tid & 127;
    int k = blk*2 + (tid >> 7);
    float v = (k < HID) ? W2l[k*HID + o] : W2r[(k-HID)*HID + o] * (1.f/NNODE);
    Wt[o*KTOT + k] = f2bf(v);
    return;
  }
  // block 128: M, cvec, W1b
  __shared__ float Mm[NNODE*NNODE];
  __shared__ float cnt[NNODE];
  for (int i = tid; i < NNODE*NNODE; i += 256) Mm[i] = 0.f;
  if (tid < NNODE) cnt[tid] = 0.f;
  __syncthreads();
  if (tid < 64) {
    int s = ei[tid], d = ei[64 + tid];
    atomicAdd(&Mm[d*NNODE + s], 1.f);
    atomicAdd(&cnt[d], 1.f);
  }
  __syncthreads();
  for (int i = tid; i < NNODE*NNODE; i += 256) {
    int n = i / NNODE;
    Mm[i] *= 1.f / fmaxf(cnt[n], 1.f);
  }
  __syncthreads();
  unsigned short* Mtb = (unsigned short*)(ws + WS_MTB);
  for (int i = tid; i < 1024; i += 256) {
    int n = i >> 5, m = i & 31;
    float v = (n < NNODE && m < NNODE) ? Mm[n*NNODE + m] : 0.f;
    Mtb[i] = f2bf(v);
  }
  if (tid < 32) {
    float a = 0.f;
    if (tid < NNODE)
      for (int n = 0; n < NNODE; ++n) a += Mm[n*NNODE + tid];
    ((float*)(ws + WS_CVEC))[tid] = a * (1.f/NNODE);
  }
  unsigned short* W1b = (unsigned short*)(ws + WS_W1B);
  for (int i = tid; i < 1024; i += 256) {
    int c = i >> 3, j = i & 7;
    float v = (j < 3) ? W1l[j*HID + c] : (j < 6) ? W1r[(j-3)*HID + c] : 0.f;
    W1b[i] = f2bf(v * 0.25f);   // 0.25 compensates kg-replicated A in phase C
  }
}

// One wave (64 threads) per block; 16 batches end-to-end; no inter-wave deps.
__global__ __launch_bounds__(64, 2) void gnn_wave(
    const float* __restrict__ x,        // [B][25][3]
    const float* __restrict__ b1,       // [128]
    const float* __restrict__ b2,       // [128]
    const unsigned char* __restrict__ ws,
    float* __restrict__ out)            // [B][128]
{
  __shared__ __align__(16) unsigned short Xtb[3][GBW][XTW];   // bf16 x[d][g][m]
  __shared__ __align__(16) unsigned short Xbf[NNODE*GBW*8];   // {agg0..2,x0..2,0,0}
  __shared__ __align__(16) unsigned short Sbf[GBW][SPAD];     // [s1 | s2*25]

  const int lane = threadIdx.x;
  const int b0   = blockIdx.x * GBW;
  const int r    = lane & 15;
  const int kg   = lane >> 4;
  const f32x4 zz = {0.f, 0.f, 0.f, 0.f};

  // ---- phase A: load 16 batches of x (300 float4), zero pads, scatter ----
  f32x4 xv[5];
  int   i4v[5];
  #pragma unroll
  for (int t = 0; t < 5; ++t) {
    int i4 = lane + t*64;
    i4v[t] = i4;
    if (i4 < 300) xv[t] = ((const f32x4*)(x + (size_t)b0*75))[i4];
  }
  #pragma unroll
  for (int t = 0; t < 6; ++t) {        // Xtb[d][g][25..31] = 0
    int idx = lane + t*64;
    if (idx < 336) {
      int d = idx / 112, rm = idx - d*112;
      Xtb[d][rm/7][25 + rm%7] = 0;
    }
  }
  #pragma unroll
  for (int t = 0; t < 7; ++t) {        // Xbf slots 6,7 = 0
    int p = lane + t*64;
    if (p < 400)
      *(unsigned int*)&Xbf[XB(p >> 4, p & 15) + 6] = 0u;
  }
  #pragma unroll
  for (int t = 0; t < 5; ++t) {
    if (i4v[t] < 300) {
      #pragma unroll
      for (int j = 0; j < 4; ++j) {
        int e = i4v[t]*4 + j;
        int g = e / 75, rm = e - g*75;
        int n = rm / 3, d = rm - n*3;
        unsigned short bv = f2bf(xv[t][j]);
        Xtb[d][g][n] = bv;
        Xbf[XB(n, g) + 3 + d] = bv;
      }
    }
  }
  __syncthreads();   // 1-wave block: pure waitcnt, no convoy

  // ---- phase B: agg via MFMA; M fragments straight from global (L2-hot) ----
  {
    const unsigned short* MtbG = (const unsigned short*)(ws + WS_MTB);
    short8 mb0 = *(const short8*)&MtbG[r*32 + kg*8];        // B[k=m][n=r]
    short8 mb1 = *(const short8*)&MtbG[(16 + r)*32 + kg*8]; // n=16+r
    #pragma unroll
    for (int d = 0; d < 3; ++d) {
      short8 af = *(const short8*)&Xtb[d][r][kg*8];         // A[g=r][k=m]
      f32x4 g0 = __builtin_amdgcn_mfma_f32_16x16x32_bf16(af, mb0, zz, 0, 0, 0);
      f32x4 g1 = __builtin_amdgcn_mfma_f32_16x16x32_bf16(af, mb1, zz, 0, 0, 0);
      #pragma unroll
      for (int q = 0; q < 4; ++q) {
        int g = kg*4 + q;
        Xbf[XB(r, g) + d] = f2bf(g0[q]);
        if (r < 9) Xbf[XB(16 + r, g) + d] = f2bf(g1[q]);
      }
    }
  }
  __syncthreads();

  // ---- phase C: stage 1, all 128 channels in-register (W1b pre-scaled 0.25) ----
  {
    const unsigned short* W1bG = (const unsigned short*)(ws + WS_W1B);
    short8 w1A[4], w1B[4];
    f32x4 cbA[4], cbB[4];
    #pragma unroll
    for (int ch = 0; ch < 4; ++ch) {
      int cA = ch*32 + r, cB = cA + 16;
      w1A[ch] = *(const short8*)&W1bG[cA * 8];
      w1B[ch] = *(const short8*)&W1bG[cB * 8];
      float bA = b1[cA], bB = b1[cB];
      cbA[ch] = (f32x4){bA, bA, bA, bA};
      cbB[ch] = (f32x4){bB, bB, bB, bB};
    }
    const float* cvG = (const float*)(ws + WS_CVEC);
    f32x2 s1[4][4] = {}, s2[4][4] = {};
    #pragma unroll 5
    for (int n = 0; n < NNODE; ++n) {
      short8 a = *(const short8*)&Xbf[XB(n, r)];   // broadcast across kg (x4, W1*0.25)
      float cv = cvG[n];
      f32x2 cvv = {cv, cv};
      #pragma unroll
      for (int ch = 0; ch < 4; ++ch) {
        f32x4 h0 = __builtin_amdgcn_mfma_f32_16x16x32_bf16(a, w1A[ch], cbA[ch], 0, 0, 0);
        f32x4 h1 = __builtin_amdgcn_mfma_f32_16x16x32_bf16(a, w1B[ch], cbB[ch], 0, 0, 0);
        #pragma unroll
        for (int q = 0; q < 4; ++q) {
          f32x2 v; v.x = fmaxf(h0[q], 0.f); v.y = fmaxf(h1[q], 0.f);
          s1[ch][q] += cvv * v;
          s2[ch][q] += v;
        }
      }
    }
    #pragma unroll
    for (int ch = 0; ch < 4; ++ch) {
      int cA = ch*32 + r, cB = cA + 16;
      #pragma unroll
      for (int q = 0; q < 4; ++q) {
        int g = kg*4 + q;
        Sbf[g][cA]       = f2bf(s1[ch][q].x);
        Sbf[g][cB]       = f2bf(s1[ch][q].y);
        Sbf[g][HID + cA] = f2bf(s2[ch][q].x);   // 1/25 folded into Wt's W2r half
        Sbf[g][HID + cB] = f2bf(s2[ch][q].y);
      }
    }
  }
  __syncthreads();

  // ---- phase D: out[16x128] = S[16x256] @ W2cat via MFMA; Wt from global ----
  {
    short8 sfr[8];
    #pragma unroll
    for (int kt = 0; kt < 8; ++kt)
      sfr[kt] = *(const short8*)&Sbf[r][kt*32 + kg*8];
    const unsigned short* Wt = (const unsigned short*)(ws + WS_WT);
    #pragma unroll
    for (int ch = 0; ch < 4; ++ch) {
      const int colA = ch*32 + r, colB = colA + 16;
      const unsigned short* WtA = Wt + (size_t)colA * KTOT;
      const unsigned short* WtB = Wt + (size_t)colB * KTOT;
      f32x4 acc0 = zz, acc1 = zz;
      #pragma unroll
      for (int kt = 0; kt < 8; ++kt) {
        const int kb = kt*32 + kg*8;
        short8 bA = *(const short8*)&WtA[kb];
        short8 bB = *(const short8*)&WtB[kb];
        acc0 = __builtin_amdgcn_mfma_f32_16x16x32_bf16(sfr[kt], bA, acc0, 0, 0, 0);
        acc1 = __builtin_amdgcn_mfma_f32_16x16x32_bf16(sfr[kt], bB, acc1, 0, 0, 0);
      }
      const float bA2 = b2[colA], bB2 = b2[colB];
      #pragma unroll
      for (int q = 0; q < 4; ++q) {
        const int row = kg*4 + q;
        out[(size_t)(b0+row)*HID + colA] = acc0[q] + bA2;
        out[(size_t)(b0+row)*HID + colB] = acc1[q] + bB2;
      }
    }
  }
}

extern "C" void kernel_launch(void* const* d_in, const int* in_sizes, int n_in,
                              void* d_out, int out_size, void* d_ws, size_t ws_size,
                              hipStream_t stream) {
  (void)n_in; (void)out_size; (void)ws_size;
  const float* x   = (const float*)d_in[0];
  const int*   ei  = (const int*)  d_in[1];
  const float* W1l = (const float*)d_in[2];
  const float* W1r = (const float*)d_in[3];
  const float* b1  = (const float*)d_in[4];
  const float* W2l = (const float*)d_in[5];
  const float* W2r = (const float*)d_in[6];
  const float* b2  = (const float*)d_in[7];
  float* out = (float*)d_out;
  unsigned char* ws = (unsigned char*)d_ws;

  const int B = in_sizes[0] / (NNODE*3);   // 16384
  prep<<<dim3(129), dim3(256), 0, stream>>>(W2l, W2r, W1l, W1r, ei, ws);
  gnn_wave<<<dim3(B / GBW), dim3(64), 0, stream>>>(x, b1, b2, ws, out);
}

// Round 11
// 19.792 us; speedup vs baseline: 2.7844x; 1.5084x over previous
//
#include <hip/hip_runtime.h>
#include <hip/hip_bf16.h>

#define NNODE 25
#define HID   128
#define GB    16
#define BLOCK 256
#define SPAD  264
#define XTW   40     // Xtb row stride (u16): 80B rows, 16B-aligned

typedef __attribute__((ext_vector_type(8))) short short8;
typedef __attribute__((ext_vector_type(4))) float f32x4;
typedef __attribute__((ext_vector_type(2))) float f32x2;

__device__ inline unsigned short f2bf(float f) {
  __hip_bfloat16 h = __float2bfloat16(f);
  unsigned short u; __builtin_memcpy(&u, &h, 2); return u;
}

// Xbf cell: node n (0..24), batch g (0..15); 8 bf16/cell; g XOR-swizzled
#define XB(n, g) (((n)*GB + ((g) ^ ((n) & 15))) * 8)

__global__ __launch_bounds__(BLOCK, 5) void gnn_one(
    const float* __restrict__ x,        // [B][25][3]
    const int*   __restrict__ ei,       // [2][64]
    const float* __restrict__ W1l,      // [3][128]
    const float* __restrict__ W1r,      // [3][128]
    const float* __restrict__ b1,       // [128]
    const float* __restrict__ W2l,      // [128][128]
    const float* __restrict__ W2r,      // [128][128]
    const float* __restrict__ b2,       // [128]
    float* __restrict__ out)            // [B][128]
{
  __shared__ float Mm[NNODE*NNODE];
  __shared__ float cnt[NNODE];
  __shared__ float cvecs[NNODE];
  __shared__ __align__(16) unsigned short Mtb[32][32];
  __shared__ __align__(16) unsigned short W1bs[HID*8];
  __shared__ __align__(16) unsigned short Xtb[3][GB][XTW];  // bf16 x[d][g][m]
  __shared__ __align__(16) unsigned short Xbf[NNODE*GB*8];  // {agg0..2, x0..2, 0, 0}
  __shared__ __align__(16) unsigned short Sbf[GB][SPAD];    // [s1 | s2/25]

  const int tid  = threadIdx.x;
  const int b0   = blockIdx.x * GB;
  const int wave = tid >> 6;
  const int lane = tid & 63;
  const int r    = lane & 15;
  const int kg   = lane >> 4;
  const f32x4 zz = {0.f, 0.f, 0.f, 0.f};

  // ---- phase A0: issue x loads; zero Mm/cnt, Xtb pad, Xbf slots 6,7 ----
  f32x4 xv[2];
  int   i4v[2];
  #pragma unroll
  for (int t = 0; t < 2; ++t) {
    int i4 = tid + t*BLOCK;
    i4v[t] = i4;
    if (i4 < GB*75/4) xv[t] = ((const f32x4*)(x + (size_t)b0*75))[i4];
  }
  for (int i = tid; i < NNODE*NNODE; i += BLOCK) Mm[i] = 0.f;
  if (tid < NNODE) cnt[tid] = 0.f;
  for (int i = tid; i < 3*GB*7; i += BLOCK) {   // Xtb[d][g][25..31] = 0 (disjoint)
    int d = i / (GB*7), rm = i % (GB*7);
    Xtb[d][rm/7][25 + rm%7] = 0;
  }
  for (int p = tid; p < NNODE*GB; p += BLOCK)   // Xbf slots 6,7 = 0
    *(unsigned int*)&Xbf[XB(p >> 4, p & 15) + 6] = 0u;
  __syncthreads();   // B1

  // ---- phase A1: edge atomics || W1bs build || x scatter ----
  if (tid < 64) {
    int s = ei[tid], d = ei[64 + tid];
    atomicAdd(&Mm[d*NNODE + s], 1.f);
    atomicAdd(&cnt[d], 1.f);
  }
  if (tid >= 64 && tid < 192) {
    int c = tid - 64;
    unsigned short* p = &W1bs[c*8];
    p[0] = f2bf(W1l[c]);  p[1] = f2bf(W1l[HID+c]);  p[2] = f2bf(W1l[2*HID+c]);
    p[3] = f2bf(W1r[c]);  p[4] = f2bf(W1r[HID+c]);  p[5] = f2bf(W1r[2*HID+c]);
    p[6] = 0;             p[7] = 0;
  }
  #pragma unroll
  for (int t = 0; t < 2; ++t) {
    if (i4v[t] < GB*75/4) {
      #pragma unroll
      for (int j = 0; j < 4; ++j) {
        int e = i4v[t]*4 + j;
        int g = e / 75, rm = e - g*75;
        int n = rm / 3, d = rm - n*3;
        unsigned short bv = f2bf(xv[t][j]);
        Xtb[d][g][n] = bv;
        Xbf[XB(n, g) + 3 + d] = bv;
      }
    }
  }
  __syncthreads();   // B2

  // ---- phase A2: normalize M -> Mtb bf16 (write normalized back for cvec) ----
  for (int i = tid; i < 1024; i += BLOCK) {
    int n = i >> 5, m = i & 31;
    float v = 0.f;
    if (n < NNODE && m < NNODE) {
      v = Mm[n*NNODE + m] / fmaxf(cnt[n], 1.f);
      Mm[n*NNODE + m] = v;
    }
    ((unsigned short*)Mtb)[i] = f2bf(v);
  }
  __syncthreads();   // B3

  // ---- phase B: agg via MFMA (waves 0..2) || cvec (wave 3) ----
  if (wave < 3) {
    const int d = wave;
    short8 mb0 = *(const short8*)&Mtb[r][kg*8];        // B[k=m][col=n], n=r
    short8 mb1 = *(const short8*)&Mtb[16 + r][kg*8];   // n=16+r (rows >=25 zero)
    short8 af  = *(const short8*)&Xtb[d][r][kg*8];     // A[row=g][k=m]
    f32x4 g0 = __builtin_amdgcn_mfma_f32_16x16x32_bf16(af, mb0, zz, 0, 0, 0);
    f32x4 g1 = __builtin_amdgcn_mfma_f32_16x16x32_bf16(af, mb1, zz, 0, 0, 0);
    #pragma unroll
    for (int q = 0; q < 4; ++q) {
      int g = kg*4 + q;                  // C row = batch (within block)
      Xbf[XB(r, g) + d] = f2bf(g0[q]);   // C col = node n = r
      if (r < 9) Xbf[XB(16 + r, g) + d] = f2bf(g1[q]);
    }
  } else if (wave == 3 && lane < NNODE) {
    float a = 0.f;
    #pragma unroll 5
    for (int n = 0; n < NNODE; ++n) a += Mm[n*NNODE + lane];
    cvecs[lane] = a * (1.f/NNODE);
  }
  __syncthreads();   // B4

  // ---- phase C: stage 1 via MFMA, 2 nodes per iteration (K slots 0,1) ----
  {
    const int c0 = wave * 32;
    const int cA = c0 + r, cB = c0 + 16 + r;
    const short8 w1A = *(const short8*)&W1bs[cA * 8];
    const short8 w1B = *(const short8*)&W1bs[cB * 8];
    const short8 z8  = {0,0,0,0,0,0,0,0};
    const short8 bA0 = (kg == 0) ? w1A : z8;
    const short8 bA1 = (kg == 1) ? w1A : z8;
    const short8 bB0 = (kg == 0) ? w1B : z8;
    const short8 bB1 = (kg == 1) ? w1B : z8;
    const float biasA = b1[cA], biasB = b1[cB];
    const f32x4 cbA = {biasA, biasA, biasA, biasA};
    const f32x4 cbB = {biasB, biasB, biasB, biasB};
    f32x2 s1[4] = {}, s2[4] = {};
    for (int ng = 0; ng < 12; ++ng) {    // nodes 2ng (slot0), 2ng+1 (slot1)
      short8 a = *(const short8*)&Xbf[XB(2*ng + (kg & 1), r)];
      f32x4 h0e = __builtin_amdgcn_mfma_f32_16x16x32_bf16(a, bA0, cbA, 0, 0, 0);
      f32x4 h1e = __builtin_amdgcn_mfma_f32_16x16x32_bf16(a, bB0, cbB, 0, 0, 0);
      f32x4 h0o = __builtin_amdgcn_mfma_f32_16x16x32_bf16(a, bA1, cbA, 0, 0, 0);
      f32x4 h1o = __builtin_amdgcn_mfma_f32_16x16x32_bf16(a, bB1, cbB, 0, 0, 0);
      const float cv0 = cvecs[2*ng], cv1 = cvecs[2*ng + 1];
      const f32x2 cvv0 = {cv0, cv0}, cvv1 = {cv1, cv1};
      #pragma unroll
      for (int q = 0; q < 4; ++q) {
        f32x2 ve; ve.x = fmaxf(h0e[q], 0.f); ve.y = fmaxf(h1e[q], 0.f);
        f32x2 vo; vo.x = fmaxf(h0o[q], 0.f); vo.y = fmaxf(h1o[q], 0.f);
        s1[q] += cvv0 * ve; s2[q] += ve;
        s1[q] += cvv1 * vo; s2[q] += vo;
      }
    }
    {  // epilogue: node 24 via slot 0 only
      short8 a = *(const short8*)&Xbf[XB(24, r)];
      f32x4 h0 = __builtin_amdgcn_mfma_f32_16x16x32_bf16(a, bA0, cbA, 0, 0, 0);
      f32x4 h1 = __builtin_amdgcn_mfma_f32_16x16x32_bf16(a, bB0, cbB, 0, 0, 0);
      const float cv = cvecs[24];
      const f32x2 cvv = {cv, cv};
      #pragma unroll
      for (int q = 0; q < 4; ++q) {
        f32x2 v; v.x = fmaxf(h0[q], 0.f); v.y = fmaxf(h1[q], 0.f);
        s1[q] += cvv * v;
        s2[q] += v;
      }
    }
    #pragma unroll
    for (int q = 0; q < 4; ++q) {
      int g = kg*4 + q;
      Sbf[g][cA]       = f2bf(s1[q].x);
      Sbf[g][cB]       = f2bf(s1[q].y);
      Sbf[g][HID + cA] = f2bf(s2[q].x * (1.f/NNODE));  // 1/25 folded here
      Sbf[g][HID + cB] = f2bf(s2[q].y * (1.f/NNODE));
    }
  }
  __syncthreads();   // B5

  // ---- phase D: out[16x128] = S[16x256] @ W2cat; W2 converted on the fly ----
  {
    const int n0 = wave * 32;
    const int colA = n0 + r, colB = n0 + 16 + r;
    f32x4 acc0 = zz, acc1 = zz;
    #pragma unroll 4
    for (int kt = 0; kt < 8; ++kt) {
      const int kb = kt*32 + kg*8;
      const float* Wsrc = (kt < 4) ? W2l : W2r;
      const int kk = (kt < 4) ? kb : kb - HID;
      short8 a = *(const short8*)&Sbf[r][kb];
      short8 bA, bB;
      #pragma unroll
      for (int j = 0; j < 8; ++j) {
        bA[j] = (short)f2bf(Wsrc[(kk+j)*HID + colA]);
        bB[j] = (short)f2bf(Wsrc[(kk+j)*HID + colB]);
      }
      acc0 = __builtin_amdgcn_mfma_f32_16x16x32_bf16(a, bA, acc0, 0, 0, 0);
      acc1 = __builtin_amdgcn_mfma_f32_16x16x32_bf16(a, bB, acc1, 0, 0, 0);
    }
    const float bA2 = b2[colA], bB2 = b2[colB];
    #pragma unroll
    for (int q = 0; q < 4; ++q) {
      const int row = kg*4 + q;
      out[(size_t)(b0+row)*HID + colA] = acc0[q] + bA2;
      out[(size_t)(b0+row)*HID + colB] = acc1[q] + bB2;
    }
  }
}

extern "C" void kernel_launch(void* const* d_in, const int* in_sizes, int n_in,
                              void* d_out, int out_size, void* d_ws, size_t ws_size,
                              hipStream_t stream) {
  (void)n_in; (void)out_size; (void)d_ws; (void)ws_size;
  const float* x   = (const float*)d_in[0];
  const int*   ei  = (const int*)  d_in[1];
  const float* W1l = (const float*)d_in[2];
  const float* W1r = (const float*)d_in[3];
  const float* b1  = (const float*)d_in[4];
  const float* W2l = (const float*)d_in[5];
  const float* W2r = (const float*)d_in[6];
  const float* b2  = (const float*)d_in[7];
  float* out = (float*)d_out;

  const int B = in_sizes[0] / (NNODE*3);   // 16384
  gnn_one<<<dim3(B / GB), dim3(BLOCK), 0, stream>>>(
      x, ei, W1l, W1r, b1, W2l, W2r, b2, out);
}